// Round 6
// baseline (1470.723 us; speedup 1.0000x reference)
//
#include <hip/hip_runtime.h>
#include <hip/hip_bf16.h>
#include <hip/hip_fp16.h>
#include <stdint.h>

#define FEATS   512
#define HIDDEN  64
#define CLASSES 16
#define EMB_DIM 7
#define ADJ_H   11
#define DEPTH   10

typedef __hip_bfloat16 bf16;
typedef __attribute__((ext_vector_type(8))) short short8;
typedef __attribute__((ext_vector_type(4))) float f32x4;

__device__ __forceinline__ float b2f(bf16 v) { return __bfloat162float(v); }

// ---------------- dtype detect: 1 = bf16, 0 = f32 ----------------
__global__ void k_detect(const unsigned short* __restrict__ xs, int* __restrict__ flag) {
    __shared__ int cnt;
    if (threadIdx.x == 0) cnt = 0;
    __syncthreads();
    int c = 0;
    for (int i = threadIdx.x; i < 4096; i += 256) {
        unsigned e = (xs[i] >> 7) & 0xFFu;
        if (e >= 134u) c++;
    }
    atomicAdd(&cnt, c);
    __syncthreads();
    if (threadIdx.x == 0) *flag = (cnt < 64) ? 1 : 0;
}

// ---------------- degree ----------------
__global__ __launch_bounds__(256) void k_deg(const int* __restrict__ edges,
                                             int* __restrict__ deg, int E) {
    int e = blockIdx.x * 256 + threadIdx.x;
    if (e < E) atomicAdd(&deg[edges[E + e]], 1);
}

// ---------------- exclusive scan ----------------
__global__ __launch_bounds__(256) void k_scan1(const int* __restrict__ deg,
                                               int* __restrict__ offs,
                                               int* __restrict__ bsum, int n) {
    __shared__ int ts[256];
    int t = threadIdx.x;
    int base = blockIdx.x * 1024 + t * 4;
    int v0 = (base + 0 < n) ? deg[base + 0] : 0;
    int v1 = (base + 1 < n) ? deg[base + 1] : 0;
    int v2 = (base + 2 < n) ? deg[base + 2] : 0;
    int v3 = (base + 3 < n) ? deg[base + 3] : 0;
    int tsum = v0 + v1 + v2 + v3;
    ts[t] = tsum;
    __syncthreads();
    for (int d = 1; d < 256; d <<= 1) {
        int add = (t >= d) ? ts[t - d] : 0;
        __syncthreads();
        ts[t] += add;
        __syncthreads();
    }
    int excl = ts[t] - tsum;
    if (base + 0 < n) offs[base + 0] = excl;
    if (base + 1 < n) offs[base + 1] = excl + v0;
    if (base + 2 < n) offs[base + 2] = excl + v0 + v1;
    if (base + 3 < n) offs[base + 3] = excl + v0 + v1 + v2;
    if (t == 255) bsum[blockIdx.x] = ts[255];
}

__global__ void k_scan2(const int* __restrict__ bsum, int* __restrict__ bpref,
                        int* __restrict__ offs, int nb, int n) {
    if (threadIdx.x == 0 && blockIdx.x == 0) {
        int run = 0;
        for (int i = 0; i < nb; ++i) { bpref[i] = run; run += bsum[i]; }
        offs[n] = run;
    }
}

__global__ __launch_bounds__(256) void k_scan3(int* __restrict__ offs,
                                               const int* __restrict__ bpref, int n) {
    int i = blockIdx.x * 256 + threadIdx.x;
    if (i < n) offs[i] += bpref[i >> 10];
}

// ---------------- CSR fill: pack (src:17b | w:15b fixed-point x16384) ----------------
__global__ __launch_bounds__(256) void k_fill(const int* __restrict__ edges,
                                              const int* __restrict__ offs,
                                              int* __restrict__ cursor,
                                              const int* __restrict__ deg,
                                              unsigned* __restrict__ ew, int E) {
    int e = blockIdx.x * 256 + threadIdx.x;
    if (e < E) {
        int src = edges[e];
        int dst = edges[E + e];
        int pos = offs[dst] + atomicAdd(&cursor[dst], 1);
        int ds = deg[src], dd = deg[dst];
        float w = (ds > 0 ? rsqrtf((float)ds) : 0.f) * (dd > 0 ? rsqrtf((float)dd) : 0.f);
        int w15 = (int)(w * 16384.0f + 0.5f);
        if (w15 > 32767) w15 = 32767;
        ew[pos] = ((unsigned)src << 15) | (unsigned)w15;
    }
}

// ---------------- MLP constants (reads raw dtype via flag) ----------------
__global__ void k_mlpconst(const void* __restrict__ emb, const void* __restrict__ W_a1,
                           const void* __restrict__ b_a1, const void* __restrict__ W_a2,
                           const void* __restrict__ b_a2, const int* __restrict__ flag,
                           float* __restrict__ C) {
    int isbf = *flag;
    auto g = [&](const void* p, int i) -> float {
        return isbf ? b2f(((const bf16*)p)[i]) : ((const float*)p)[i];
    };
    int j = threadIdx.x;
    if (j < ADJ_H) {
        float c = g(b_a1, j);
        for (int k = 0; k < EMB_DIM; ++k)
            c += g(emb, k) * g(W_a1, (2 + k) * ADJ_H + j);
        C[j]      = c;
        C[11 + j] = g(W_a1, 0 * ADJ_H + j);
        C[22 + j] = g(W_a1, 1 * ADJ_H + j);
        C[33 + j] = g(W_a2, j);
    }
    if (j == 0) C[44] = g(b_a2, 0);
}

// ---------------- MFMA GEMM: h = x @ W + b -> fp16 [node][64] ----------------
__global__ __launch_bounds__(256) void k_gemm_mfma(const void* __restrict__ xraw,
                                                   const int* __restrict__ flag,
                                                   const void* __restrict__ Wraw,
                                                   const void* __restrict__ braw,
                                                   __half* __restrict__ out, int n) {
    __shared__ short Wt[64 * 520];
    int t = threadIdx.x;
    int isbf = *flag;
    if (isbf) {
        const unsigned short* wr = (const unsigned short*)Wraw;
        for (int e = t; e < FEATS * HIDDEN; e += 256)
            Wt[(e & 63) * 520 + (e >> 6)] = (short)wr[e];
    } else {
        const float* wr = (const float*)Wraw;
        for (int e = t; e < FEATS * HIDDEN; e += 256)
            Wt[(e & 63) * 520 + (e >> 6)] = (short)(__float_as_uint(wr[e]) >> 16);
    }
    __syncthreads();

    int wv = t >> 6;
    int lane = t & 63;
    int quad = lane >> 4, l16 = lane & 15;
    int rowbase = blockIdx.x * 256 + wv * 64;

    f32x4 acc[4][4];
    #pragma unroll
    for (int a = 0; a < 4; ++a)
        #pragma unroll
        for (int b = 0; b < 4; ++b)
            acc[a][b] = (f32x4){0.f, 0.f, 0.f, 0.f};

    if (isbf) {
        const short* x = (const short*)xraw;
        for (int ks = 0; ks < 16; ++ks) {
            short8 bfr[4];
            #pragma unroll
            for (int nt = 0; nt < 4; ++nt)
                bfr[nt] = *(const short8*)&Wt[(nt * 16 + l16) * 520 + ks * 32 + quad * 8];
            #pragma unroll
            for (int rt = 0; rt < 4; ++rt) {
                int arow = rowbase + rt * 16 + l16;
                if (arow >= n) arow = n - 1;
                short8 a = *(const short8*)(x + (size_t)arow * FEATS + ks * 32 + quad * 8);
                #pragma unroll
                for (int nt = 0; nt < 4; ++nt)
                    acc[rt][nt] = __builtin_amdgcn_mfma_f32_16x16x32_bf16(a, bfr[nt], acc[rt][nt], 0, 0, 0);
            }
        }
    } else {
        const float* x = (const float*)xraw;
        for (int ks = 0; ks < 16; ++ks) {
            short8 bfr[4];
            #pragma unroll
            for (int nt = 0; nt < 4; ++nt)
                bfr[nt] = *(const short8*)&Wt[(nt * 16 + l16) * 520 + ks * 32 + quad * 8];
            #pragma unroll
            for (int rt = 0; rt < 4; ++rt) {
                int arow = rowbase + rt * 16 + l16;
                if (arow >= n) arow = n - 1;
                const float* ap = x + (size_t)arow * FEATS + ks * 32 + quad * 8;
                short8 a;
                #pragma unroll
                for (int j = 0; j < 8; ++j)
                    a[j] = (short)(__float_as_uint(ap[j]) >> 16);
                #pragma unroll
                for (int nt = 0; nt < 4; ++nt)
                    acc[rt][nt] = __builtin_amdgcn_mfma_f32_16x16x32_bf16(a, bfr[nt], acc[rt][nt], 0, 0, 0);
            }
        }
    }

    float bias[4];
    #pragma unroll
    for (int nt = 0; nt < 4; ++nt)
        bias[nt] = isbf ? b2f(((const bf16*)braw)[nt * 16 + l16])
                        : ((const float*)braw)[nt * 16 + l16];

    #pragma unroll
    for (int rt = 0; rt < 4; ++rt)
        #pragma unroll
        for (int nt = 0; nt < 4; ++nt) {
            #pragma unroll
            for (int r = 0; r < 4; ++r) {
                int grow = rowbase + rt * 16 + quad * 4 + r;
                if (grow < n)
                    out[(size_t)grow * HIDDEN + nt * 16 + l16] =
                        __float2half(acc[rt][nt][r] + bias[nt]);
            }
        }
}

// ---------------- conv: 1 node/wave, lane = channel, scalar edge stream ----------------
// hout[node][l] = 0.9 * sum_e w_e * hin[src_e][l] + 0.1 * h0[node][l].
// node is wave-uniform (readfirstlane) -> offs/ew reads become s_loads;
// per edge: 1 coalesced 128-B row gather + cvt + fma per lane. No shuffles, no LDS.
__global__ __launch_bounds__(256) void k_conv(const int* __restrict__ offs,
                                              const unsigned* __restrict__ ew,
                                              const __half* __restrict__ hin,
                                              const __half* __restrict__ h0,
                                              __half* __restrict__ hout, int n) {
    int node = __builtin_amdgcn_readfirstlane(blockIdx.x * 4 + ((int)threadIdx.x >> 6));
    if (node >= n) return;
    int lane = threadIdx.x & 63;
    int start = offs[node];
    int end   = offs[node + 1];
    float acc0 = 0.f, acc1 = 0.f;
    int p = start;
    for (; p + 4 <= end; p += 4) {
        unsigned u0 = ew[p + 0];
        unsigned u1 = ew[p + 1];
        unsigned u2 = ew[p + 2];
        unsigned u3 = ew[p + 3];
        float v0 = __half2float(hin[(size_t)(u0 >> 15) * HIDDEN + lane]);
        float v1 = __half2float(hin[(size_t)(u1 >> 15) * HIDDEN + lane]);
        float v2 = __half2float(hin[(size_t)(u2 >> 15) * HIDDEN + lane]);
        float v3 = __half2float(hin[(size_t)(u3 >> 15) * HIDDEN + lane]);
        acc0 += (float)(u0 & 0x7FFFu) * v0;
        acc1 += (float)(u1 & 0x7FFFu) * v1;
        acc0 += (float)(u2 & 0x7FFFu) * v2;
        acc1 += (float)(u3 & 0x7FFFu) * v3;
    }
    for (; p < end; ++p) {
        unsigned u = ew[p];
        acc0 += (float)(u & 0x7FFFu) * __half2float(hin[(size_t)(u >> 15) * HIDDEN + lane]);
    }
    float acc = (acc0 + acc1) * (1.0f / 16384.0f);
    float h0v = __half2float(h0[(size_t)node * HIDDEN + lane]);
    hout[(size_t)node * HIDDEN + lane] = __float2half(0.9f * acc + 0.1f * h0v);
}

// ---------------- elementwise edge-MLP (in-place on h0) ----------------
__global__ __launch_bounds__(256) void k_mlp(__half* __restrict__ h0io,
                                             const __half* __restrict__ hc,
                                             const float* __restrict__ C, int total2) {
    int i = blockIdx.x * 256 + threadIdx.x;
    if (i >= total2) return;
    float2 hv  = __half22float2(((const __half2*)hc)[i]);
    float2 h0v = __half22float2(((const __half2*)h0io)[i]);
    float sx = C[44], sy = C[44];
    #pragma unroll
    for (int j = 0; j < ADJ_H; ++j) {
        float bj = C[j], wh = C[11 + j], w0 = C[22 + j], wo = C[33 + j];
        float zx = bj + hv.x * wh + h0v.x * w0;
        float zy = bj + hv.y * wh + h0v.y * w0;
        zx = (zx > 0.f) ? zx : 0.01f * zx;
        zy = (zy > 0.f) ? zy : 0.01f * zy;
        sx += zx * wo;
        sy += zy * wo;
    }
    ((__half2*)h0io)[i] = __floats2half2_rn(0.5f * sx, 0.5f * sy);
}

// ---------------- classifier ----------------
__global__ __launch_bounds__(256) void k_cls(const __half* __restrict__ h,
                                             const void* __restrict__ Wcraw,
                                             const void* __restrict__ bcraw,
                                             void* __restrict__ outraw,
                                             const int* __restrict__ flag, int n) {
    __shared__ float hs[64][65];
    __shared__ float ws[64 * 16];
    __shared__ float bs[16];
    int t = threadIdx.x;
    int base = blockIdx.x * 64;
    int isbf = *flag;
    for (int it = 0; it < 16; ++it) {
        int e = it * 256 + t;
        int rr = e >> 6, cc = e & 63;
        int g = base + rr;
        hs[rr][cc] = (g < n) ? __half2float(h[(size_t)g * HIDDEN + cc]) : 0.f;
    }
    for (int it = 0; it < 4; ++it) {
        int e = it * 256 + t;
        ws[e] = isbf ? b2f(((const bf16*)Wcraw)[e]) : ((const float*)Wcraw)[e];
    }
    if (t < 16) bs[t] = isbf ? b2f(((const bf16*)bcraw)[t]) : ((const float*)bcraw)[t];
    __syncthreads();
    for (int q = 0; q < 4; ++q) {
        int e = q * 256 + t;
        int node = e >> 4, cls = e & 15;
        float acc = bs[cls];
        #pragma unroll 8
        for (int k = 0; k < HIDDEN; ++k)
            acc += hs[node][k] * ws[k * 16 + cls];
        int g = base + node;
        if (g < n) {
            size_t oi = (size_t)g * CLASSES + cls;
            if (isbf) ((bf16*)outraw)[oi] = __float2bfloat16(acc);
            else      ((float*)outraw)[oi] = acc;
        }
    }
}

extern "C" void kernel_launch(void* const* d_in, const int* in_sizes, int n_in,
                              void* d_out, int out_size, void* d_ws, size_t ws_size,
                              hipStream_t stream) {
    const void* x     = d_in[0];
    const int*  edges = (const int*)d_in[1];
    const void* W_dim = d_in[2];
    const void* b_dim = d_in[3];
    const void* emb   = d_in[4];
    const void* W_a1  = d_in[5];
    const void* b_a1  = d_in[6];
    const void* W_a2  = d_in[7];
    const void* b_a2  = d_in[8];
    const void* Wcls  = d_in[9];
    const void* bcls  = d_in[10];

    const int n = in_sizes[0] / FEATS;     // 100000
    const int E = in_sizes[1] / 2;         // 1600000

    char* w = (char*)d_ws;
    size_t off = 0;
    auto alloc = [&](size_t bytes) -> void* {
        void* p = w + off;
        off = (off + bytes + 255) & ~(size_t)255;
        return p;
    };
    int*      deg    = (int*)     alloc((size_t)n * 4);
    int*      cursor = (int*)     alloc((size_t)n * 4);
    int*      offs   = (int*)     alloc((size_t)(n + 1) * 4);
    int*      bsum   = (int*)     alloc(4096 * 4);
    int*      bpref  = (int*)     alloc(4096 * 4);
    unsigned* ew     = (unsigned*)alloc((size_t)E * 4);
    float*    consts = (float*)   alloc(64 * 4);
    int*      flag   = (int*)     alloc(256);
    __half*   buf0   = (__half*)  alloc((size_t)n * HIDDEN * 2);
    __half*   bufA   = (__half*)  alloc((size_t)n * HIDDEN * 2);
    __half*   bufB   = (__half*)  alloc((size_t)n * HIDDEN * 2);

    int gE = (E + 255) / 256;
    int gN = (n + 255) / 256;
    int nb = (n + 1023) / 1024;
    int gConv = (n + 3) / 4;   // 4 waves/block, 1 node/wave

    hipMemsetAsync(deg, 0, ((char*)cursor - (char*)deg) + (size_t)n * 4, stream);

    k_detect<<<1, 256, 0, stream>>>((const unsigned short*)x, flag);

    k_deg  <<<gE, 256, 0, stream>>>(edges, deg, E);
    k_scan1<<<nb, 256, 0, stream>>>(deg, offs, bsum, n);
    k_scan2<<<1, 64, 0, stream>>>(bsum, bpref, offs, nb, n);
    k_scan3<<<gN, 256, 0, stream>>>(offs, bpref, n);
    k_fill <<<gE, 256, 0, stream>>>(edges, offs, cursor, deg, ew, E);

    k_mlpconst<<<1, 64, 0, stream>>>(emb, W_a1, b_a1, W_a2, b_a2, flag, consts);

    k_gemm_mfma<<<(n + 255) / 256, 256, 0, stream>>>(x, flag, W_dim, b_dim, buf0, n);

    const __half* hin = buf0;
    for (int i = 0; i < DEPTH; ++i) {
        __half* ho = (i & 1) ? bufB : bufA;
        k_conv<<<gConv, 256, 0, stream>>>(offs, ew, hin, buf0, ho, n);
        hin = ho;
    }
    k_mlp<<<(n * (HIDDEN / 2) + 255) / 256, 256, 0, stream>>>(buf0, hin, consts, n * (HIDDEN / 2));

    hin = buf0;
    for (int i = 0; i < DEPTH; ++i) {
        __half* ho = (i & 1) ? bufB : bufA;
        k_conv<<<gConv, 256, 0, stream>>>(offs, ew, hin, buf0, ho, n);
        hin = ho;
    }
    k_cls<<<(n + 63) / 64, 256, 0, stream>>>(hin, Wcls, bcls, d_out, flag, n);
}

// Round 7
// 1150.313 us; speedup vs baseline: 1.2785x; 1.2785x over previous
//
#include <hip/hip_runtime.h>
#include <hip/hip_bf16.h>
#include <hip/hip_fp16.h>
#include <stdint.h>

#define FEATS   512
#define HIDDEN  64
#define CLASSES 16
#define EMB_DIM 7
#define ADJ_H   11
#define DEPTH   10

typedef __hip_bfloat16 bf16;
typedef __attribute__((ext_vector_type(8))) short short8;
typedef __attribute__((ext_vector_type(4))) float f32x4;

__device__ __forceinline__ float b2f(bf16 v) { return __bfloat162float(v); }

// ---------------- dtype detect: 1 = bf16, 0 = f32 ----------------
__global__ void k_detect(const unsigned short* __restrict__ xs, int* __restrict__ flag) {
    __shared__ int cnt;
    if (threadIdx.x == 0) cnt = 0;
    __syncthreads();
    int c = 0;
    for (int i = threadIdx.x; i < 4096; i += 256) {
        unsigned e = (xs[i] >> 7) & 0xFFu;
        if (e >= 134u) c++;
    }
    atomicAdd(&cnt, c);
    __syncthreads();
    if (threadIdx.x == 0) *flag = (cnt < 64) ? 1 : 0;
}

// ---------------- degree ----------------
__global__ __launch_bounds__(256) void k_deg(const int* __restrict__ edges,
                                             int* __restrict__ deg, int E) {
    int e = blockIdx.x * 256 + threadIdx.x;
    if (e < E) atomicAdd(&deg[edges[E + e]], 1);
}

// ---------------- exclusive scan ----------------
__global__ __launch_bounds__(256) void k_scan1(const int* __restrict__ deg,
                                               int* __restrict__ offs,
                                               int* __restrict__ bsum, int n) {
    __shared__ int ts[256];
    int t = threadIdx.x;
    int base = blockIdx.x * 1024 + t * 4;
    int v0 = (base + 0 < n) ? deg[base + 0] : 0;
    int v1 = (base + 1 < n) ? deg[base + 1] : 0;
    int v2 = (base + 2 < n) ? deg[base + 2] : 0;
    int v3 = (base + 3 < n) ? deg[base + 3] : 0;
    int tsum = v0 + v1 + v2 + v3;
    ts[t] = tsum;
    __syncthreads();
    for (int d = 1; d < 256; d <<= 1) {
        int add = (t >= d) ? ts[t - d] : 0;
        __syncthreads();
        ts[t] += add;
        __syncthreads();
    }
    int excl = ts[t] - tsum;
    if (base + 0 < n) offs[base + 0] = excl;
    if (base + 1 < n) offs[base + 1] = excl + v0;
    if (base + 2 < n) offs[base + 2] = excl + v0 + v1;
    if (base + 3 < n) offs[base + 3] = excl + v0 + v1 + v2;
    if (t == 255) bsum[blockIdx.x] = ts[255];
}

__global__ void k_scan2(const int* __restrict__ bsum, int* __restrict__ bpref,
                        int* __restrict__ offs, int nb, int n) {
    if (threadIdx.x == 0 && blockIdx.x == 0) {
        int run = 0;
        for (int i = 0; i < nb; ++i) { bpref[i] = run; run += bsum[i]; }
        offs[n] = run;
    }
}

__global__ __launch_bounds__(256) void k_scan3(int* __restrict__ offs,
                                               const int* __restrict__ bpref, int n) {
    int i = blockIdx.x * 256 + threadIdx.x;
    if (i < n) offs[i] += bpref[i >> 10];
}

// ---------------- CSR fill: pack (src:17b | w:15b fixed-point x16384) ----------------
__global__ __launch_bounds__(256) void k_fill(const int* __restrict__ edges,
                                              const int* __restrict__ offs,
                                              int* __restrict__ cursor,
                                              const int* __restrict__ deg,
                                              unsigned* __restrict__ ew, int E) {
    int e = blockIdx.x * 256 + threadIdx.x;
    if (e < E) {
        int src = edges[e];
        int dst = edges[E + e];
        int pos = offs[dst] + atomicAdd(&cursor[dst], 1);
        int ds = deg[src], dd = deg[dst];
        float w = (ds > 0 ? rsqrtf((float)ds) : 0.f) * (dd > 0 ? rsqrtf((float)dd) : 0.f);
        int w15 = (int)(w * 16384.0f + 0.5f);
        if (w15 > 32767) w15 = 32767;
        ew[pos] = ((unsigned)src << 15) | (unsigned)w15;
    }
}

// ---------------- MLP constants (reads raw dtype via flag) ----------------
__global__ void k_mlpconst(const void* __restrict__ emb, const void* __restrict__ W_a1,
                           const void* __restrict__ b_a1, const void* __restrict__ W_a2,
                           const void* __restrict__ b_a2, const int* __restrict__ flag,
                           float* __restrict__ C) {
    int isbf = *flag;
    auto g = [&](const void* p, int i) -> float {
        return isbf ? b2f(((const bf16*)p)[i]) : ((const float*)p)[i];
    };
    int j = threadIdx.x;
    if (j < ADJ_H) {
        float c = g(b_a1, j);
        for (int k = 0; k < EMB_DIM; ++k)
            c += g(emb, k) * g(W_a1, (2 + k) * ADJ_H + j);
        C[j]      = c;
        C[11 + j] = g(W_a1, 0 * ADJ_H + j);
        C[22 + j] = g(W_a1, 1 * ADJ_H + j);
        C[33 + j] = g(W_a2, j);
    }
    if (j == 0) C[44] = g(b_a2, 0);
}

// ---------------- MFMA GEMM: h = x @ W + b -> fp16 [node][64] ----------------
__global__ __launch_bounds__(256) void k_gemm_mfma(const void* __restrict__ xraw,
                                                   const int* __restrict__ flag,
                                                   const void* __restrict__ Wraw,
                                                   const void* __restrict__ braw,
                                                   __half* __restrict__ out, int n) {
    __shared__ short Wt[64 * 520];
    int t = threadIdx.x;
    int isbf = *flag;
    if (isbf) {
        const unsigned short* wr = (const unsigned short*)Wraw;
        for (int e = t; e < FEATS * HIDDEN; e += 256)
            Wt[(e & 63) * 520 + (e >> 6)] = (short)wr[e];
    } else {
        const float* wr = (const float*)Wraw;
        for (int e = t; e < FEATS * HIDDEN; e += 256)
            Wt[(e & 63) * 520 + (e >> 6)] = (short)(__float_as_uint(wr[e]) >> 16);
    }
    __syncthreads();

    int wv = t >> 6;
    int lane = t & 63;
    int quad = lane >> 4, l16 = lane & 15;
    int rowbase = blockIdx.x * 256 + wv * 64;

    f32x4 acc[4][4];
    #pragma unroll
    for (int a = 0; a < 4; ++a)
        #pragma unroll
        for (int b = 0; b < 4; ++b)
            acc[a][b] = (f32x4){0.f, 0.f, 0.f, 0.f};

    if (isbf) {
        const short* x = (const short*)xraw;
        for (int ks = 0; ks < 16; ++ks) {
            short8 bfr[4];
            #pragma unroll
            for (int nt = 0; nt < 4; ++nt)
                bfr[nt] = *(const short8*)&Wt[(nt * 16 + l16) * 520 + ks * 32 + quad * 8];
            #pragma unroll
            for (int rt = 0; rt < 4; ++rt) {
                int arow = rowbase + rt * 16 + l16;
                if (arow >= n) arow = n - 1;
                short8 a = *(const short8*)(x + (size_t)arow * FEATS + ks * 32 + quad * 8);
                #pragma unroll
                for (int nt = 0; nt < 4; ++nt)
                    acc[rt][nt] = __builtin_amdgcn_mfma_f32_16x16x32_bf16(a, bfr[nt], acc[rt][nt], 0, 0, 0);
            }
        }
    } else {
        const float* x = (const float*)xraw;
        for (int ks = 0; ks < 16; ++ks) {
            short8 bfr[4];
            #pragma unroll
            for (int nt = 0; nt < 4; ++nt)
                bfr[nt] = *(const short8*)&Wt[(nt * 16 + l16) * 520 + ks * 32 + quad * 8];
            #pragma unroll
            for (int rt = 0; rt < 4; ++rt) {
                int arow = rowbase + rt * 16 + l16;
                if (arow >= n) arow = n - 1;
                const float* ap = x + (size_t)arow * FEATS + ks * 32 + quad * 8;
                short8 a;
                #pragma unroll
                for (int j = 0; j < 8; ++j)
                    a[j] = (short)(__float_as_uint(ap[j]) >> 16);
                #pragma unroll
                for (int nt = 0; nt < 4; ++nt)
                    acc[rt][nt] = __builtin_amdgcn_mfma_f32_16x16x32_bf16(a, bfr[nt], acc[rt][nt], 0, 0, 0);
            }
        }
    }

    float bias[4];
    #pragma unroll
    for (int nt = 0; nt < 4; ++nt)
        bias[nt] = isbf ? b2f(((const bf16*)braw)[nt * 16 + l16])
                        : ((const float*)braw)[nt * 16 + l16];

    #pragma unroll
    for (int rt = 0; rt < 4; ++rt)
        #pragma unroll
        for (int nt = 0; nt < 4; ++nt) {
            #pragma unroll
            for (int r = 0; r < 4; ++r) {
                int grow = rowbase + rt * 16 + quad * 4 + r;
                if (grow < n)
                    out[(size_t)grow * HIDDEN + nt * 16 + l16] =
                        __float2half(acc[rt][nt][r] + bias[nt]);
            }
        }
}

// ---------------- conv: 8 nodes/wave, 8 lanes/node, 4-deep gather pipeline ----------------
// Subwave s (8 lanes x uint4 = one 128-B fp16 row) owns node wv*8+s. Edge loop
// unrolled 4-deep: 4 independent row gathers in flight per subwave -> up to 32
// outstanding lines/wave. Edge words are subwave-uniform broadcast loads.
__global__ __launch_bounds__(256) void k_conv(const int* __restrict__ offs,
                                              const unsigned* __restrict__ ew,
                                              const __half* __restrict__ hin,
                                              const __half* __restrict__ h0,
                                              __half* __restrict__ hout, int n) {
    int wv = (blockIdx.x * 256 + threadIdx.x) >> 6;
    int lane = threadIdx.x & 63;
    int sub = lane >> 3;          // 0..7 : node within wave
    int li  = lane & 7;           // 8 lanes x 8 fp16 = 128-B row
    int node = wv * 8 + sub;
    bool valid = node < n;
    int start = valid ? offs[node] : 0;
    int end   = valid ? offs[node + 1] : 0;

    float acc[8];
    #pragma unroll
    for (int j = 0; j < 8; ++j) acc[j] = 0.f;

    int p = start;
    for (; p + 4 <= end; p += 4) {
        unsigned u0 = ew[p + 0];
        unsigned u1 = ew[p + 1];
        unsigned u2 = ew[p + 2];
        unsigned u3 = ew[p + 3];
        uint4 r0 = *(const uint4*)(hin + (size_t)(u0 >> 15) * HIDDEN + li * 8);
        uint4 r1 = *(const uint4*)(hin + (size_t)(u1 >> 15) * HIDDEN + li * 8);
        uint4 r2 = *(const uint4*)(hin + (size_t)(u2 >> 15) * HIDDEN + li * 8);
        uint4 r3 = *(const uint4*)(hin + (size_t)(u3 >> 15) * HIDDEN + li * 8);
        float w0 = (float)(u0 & 0x7FFFu);
        float w1 = (float)(u1 & 0x7FFFu);
        float w2 = (float)(u2 & 0x7FFFu);
        float w3 = (float)(u3 & 0x7FFFu);
        const unsigned* q;
        q = &r0.x;
        #pragma unroll
        for (int j = 0; j < 4; ++j) {
            float2 f = __half22float2(*(const __half2*)&q[j]);
            acc[2*j]   += w0 * f.x;
            acc[2*j+1] += w0 * f.y;
        }
        q = &r1.x;
        #pragma unroll
        for (int j = 0; j < 4; ++j) {
            float2 f = __half22float2(*(const __half2*)&q[j]);
            acc[2*j]   += w1 * f.x;
            acc[2*j+1] += w1 * f.y;
        }
        q = &r2.x;
        #pragma unroll
        for (int j = 0; j < 4; ++j) {
            float2 f = __half22float2(*(const __half2*)&q[j]);
            acc[2*j]   += w2 * f.x;
            acc[2*j+1] += w2 * f.y;
        }
        q = &r3.x;
        #pragma unroll
        for (int j = 0; j < 4; ++j) {
            float2 f = __half22float2(*(const __half2*)&q[j]);
            acc[2*j]   += w3 * f.x;
            acc[2*j+1] += w3 * f.y;
        }
    }
    for (; p < end; ++p) {
        unsigned u = ew[p];
        uint4 r = *(const uint4*)(hin + (size_t)(u >> 15) * HIDDEN + li * 8);
        float w = (float)(u & 0x7FFFu);
        const unsigned* q = &r.x;
        #pragma unroll
        for (int j = 0; j < 4; ++j) {
            float2 f = __half22float2(*(const __half2*)&q[j]);
            acc[2*j]   += w * f.x;
            acc[2*j+1] += w * f.y;
        }
    }

    if (valid) {
        size_t o = (size_t)node * HIDDEN + li * 8;
        uint4 hv = *(const uint4*)(h0 + o);
        const unsigned* q = &hv.x;
        uint4 ov;
        unsigned* po = &ov.x;
        #pragma unroll
        for (int j = 0; j < 4; ++j) {
            float2 g = __half22float2(*(const __half2*)&q[j]);
            __half2 r = __floats2half2_rn(
                0.9f * (1.0f / 16384.0f) * acc[2*j]   + 0.1f * g.x,
                0.9f * (1.0f / 16384.0f) * acc[2*j+1] + 0.1f * g.y);
            po[j] = *(unsigned*)&r;
        }
        *(uint4*)(hout + o) = ov;
    }
}

// ---------------- elementwise edge-MLP (in-place on h0) ----------------
__global__ __launch_bounds__(256) void k_mlp(__half* __restrict__ h0io,
                                             const __half* __restrict__ hc,
                                             const float* __restrict__ C, int total2) {
    int i = blockIdx.x * 256 + threadIdx.x;
    if (i >= total2) return;
    float2 hv  = __half22float2(((const __half2*)hc)[i]);
    float2 h0v = __half22float2(((const __half2*)h0io)[i]);
    float sx = C[44], sy = C[44];
    #pragma unroll
    for (int j = 0; j < ADJ_H; ++j) {
        float bj = C[j], wh = C[11 + j], w0 = C[22 + j], wo = C[33 + j];
        float zx = bj + hv.x * wh + h0v.x * w0;
        float zy = bj + hv.y * wh + h0v.y * w0;
        zx = (zx > 0.f) ? zx : 0.01f * zx;
        zy = (zy > 0.f) ? zy : 0.01f * zy;
        sx += zx * wo;
        sy += zy * wo;
    }
    ((__half2*)h0io)[i] = __floats2half2_rn(0.5f * sx, 0.5f * sy);
}

// ---------------- classifier ----------------
__global__ __launch_bounds__(256) void k_cls(const __half* __restrict__ h,
                                             const void* __restrict__ Wcraw,
                                             const void* __restrict__ bcraw,
                                             void* __restrict__ outraw,
                                             const int* __restrict__ flag, int n) {
    __shared__ float hs[64][65];
    __shared__ float ws[64 * 16];
    __shared__ float bs[16];
    int t = threadIdx.x;
    int base = blockIdx.x * 64;
    int isbf = *flag;
    for (int it = 0; it < 16; ++it) {
        int e = it * 256 + t;
        int rr = e >> 6, cc = e & 63;
        int g = base + rr;
        hs[rr][cc] = (g < n) ? __half2float(h[(size_t)g * HIDDEN + cc]) : 0.f;
    }
    for (int it = 0; it < 4; ++it) {
        int e = it * 256 + t;
        ws[e] = isbf ? b2f(((const bf16*)Wcraw)[e]) : ((const float*)Wcraw)[e];
    }
    if (t < 16) bs[t] = isbf ? b2f(((const bf16*)bcraw)[t]) : ((const float*)bcraw)[t];
    __syncthreads();
    for (int q = 0; q < 4; ++q) {
        int e = q * 256 + t;
        int node = e >> 4, cls = e & 15;
        float acc = bs[cls];
        #pragma unroll 8
        for (int k = 0; k < HIDDEN; ++k)
            acc += hs[node][k] * ws[k * 16 + cls];
        int g = base + node;
        if (g < n) {
            size_t oi = (size_t)g * CLASSES + cls;
            if (isbf) ((bf16*)outraw)[oi] = __float2bfloat16(acc);
            else      ((float*)outraw)[oi] = acc;
        }
    }
}

extern "C" void kernel_launch(void* const* d_in, const int* in_sizes, int n_in,
                              void* d_out, int out_size, void* d_ws, size_t ws_size,
                              hipStream_t stream) {
    const void* x     = d_in[0];
    const int*  edges = (const int*)d_in[1];
    const void* W_dim = d_in[2];
    const void* b_dim = d_in[3];
    const void* emb   = d_in[4];
    const void* W_a1  = d_in[5];
    const void* b_a1  = d_in[6];
    const void* W_a2  = d_in[7];
    const void* b_a2  = d_in[8];
    const void* Wcls  = d_in[9];
    const void* bcls  = d_in[10];

    const int n = in_sizes[0] / FEATS;     // 100000
    const int E = in_sizes[1] / 2;         // 1600000

    char* w = (char*)d_ws;
    size_t off = 0;
    auto alloc = [&](size_t bytes) -> void* {
        void* p = w + off;
        off = (off + bytes + 255) & ~(size_t)255;
        return p;
    };
    int*      deg    = (int*)     alloc((size_t)n * 4);
    int*      cursor = (int*)     alloc((size_t)n * 4);
    int*      offs   = (int*)     alloc((size_t)(n + 1) * 4);
    int*      bsum   = (int*)     alloc(4096 * 4);
    int*      bpref  = (int*)     alloc(4096 * 4);
    unsigned* ew     = (unsigned*)alloc((size_t)E * 4);
    float*    consts = (float*)   alloc(64 * 4);
    int*      flag   = (int*)     alloc(256);
    __half*   buf0   = (__half*)  alloc((size_t)n * HIDDEN * 2);
    __half*   bufA   = (__half*)  alloc((size_t)n * HIDDEN * 2);
    __half*   bufB   = (__half*)  alloc((size_t)n * HIDDEN * 2);

    int gE = (E + 255) / 256;
    int gN = (n + 255) / 256;
    int nb = (n + 1023) / 1024;
    int gConv = (n + 31) / 32;   // 4 waves/block, 8 nodes/wave

    hipMemsetAsync(deg, 0, ((char*)cursor - (char*)deg) + (size_t)n * 4, stream);

    k_detect<<<1, 256, 0, stream>>>((const unsigned short*)x, flag);

    k_deg  <<<gE, 256, 0, stream>>>(edges, deg, E);
    k_scan1<<<nb, 256, 0, stream>>>(deg, offs, bsum, n);
    k_scan2<<<1, 64, 0, stream>>>(bsum, bpref, offs, nb, n);
    k_scan3<<<gN, 256, 0, stream>>>(offs, bpref, n);
    k_fill <<<gE, 256, 0, stream>>>(edges, offs, cursor, deg, ew, E);

    k_mlpconst<<<1, 64, 0, stream>>>(emb, W_a1, b_a1, W_a2, b_a2, flag, consts);

    k_gemm_mfma<<<(n + 255) / 256, 256, 0, stream>>>(x, flag, W_dim, b_dim, buf0, n);

    const __half* hin = buf0;
    for (int i = 0; i < DEPTH; ++i) {
        __half* ho = (i & 1) ? bufB : bufA;
        k_conv<<<gConv, 256, 0, stream>>>(offs, ew, hin, buf0, ho, n);
        hin = ho;
    }
    k_mlp<<<(n * (HIDDEN / 2) + 255) / 256, 256, 0, stream>>>(buf0, hin, consts, n * (HIDDEN / 2));

    hin = buf0;
    for (int i = 0; i < DEPTH; ++i) {
        __half* ho = (i & 1) ? bufB : bufA;
        k_conv<<<gConv, 256, 0, stream>>>(offs, ew, hin, buf0, ho, n);
        hin = ho;
    }
    k_cls<<<(n + 63) / 64, 256, 0, stream>>>(hin, Wcls, bcls, d_out, flag, n);
}